// Round 6
// baseline (139.512 us; speedup 1.0000x reference)
//
#include <hip/hip_runtime.h>
#include <hip/hip_bf16.h>

using short8  = __attribute__((ext_vector_type(8))) short;
using floatx4 = __attribute__((ext_vector_type(4))) float;

#define CC 192
#define CN 4096
#define NHEAD 6
#define DHEAD 32

__device__ __forceinline__ float bf2f(short s) {
    return __uint_as_float(((unsigned)(unsigned short)s) << 16);
}
__device__ __forceinline__ short f2bf(float f) {
    __hip_bfloat16 h = __float2bfloat16(f);
    return *(short*)&h;
}

// ---------------- kernel 0: rope cos/sin table ----------------
__global__ void k0_table(float2* __restrict__ tab) {
    int idx = blockIdx.x * 256 + threadIdx.x;
    if (idx >= CN * 96) return;
    int n = idx / 96, c2 = idx - n * 96;
    int h = n >> 6, w = n & 63;
    int i = (c2 < 48) ? c2 : c2 - 48;
    float pos = (float)((c2 < 48) ? h : w);
    float theta = expf(-(float)i * (9.210340371976184f / 48.0f)); // ln(10000)/48
    float ang = pos * theta;
    tab[idx] = make_float2(cosf(ang), sinf(ang));
}

__global__ void k_zero(float* __restrict__ p, int n) {
    int i = blockIdx.x * 256 + threadIdx.x;
    if (i < n) p[i] = 0.f;
}

// ---------------- kernel 0w: pre-fragment qk_w into bf16 MFMA-B layout ----------------
// wfr[((nig*6+ks)*64 + lane) * 8 + j] = bf16(qkw[col][k]),
// col = nig*16 + (lane&15), k = ks*32 + (lane>>4)*8 + j
__global__ void k0_wfrag(const float* __restrict__ qkw, __hip_bfloat16* __restrict__ wfr) {
    int tid = blockIdx.x * 256 + threadIdx.x;     // 0..9215
    if (tid >= 24 * 6 * 64) return;
    int lane = tid & 63;
    int ks = (tid >> 6) % 6;
    int nig = tid / (6 * 64);
    int col = nig * 16 + (lane & 15);
    int k = ks * 32 + (lane >> 4) * 8;
    const float4* src = (const float4*)(qkw + (long)col * CC + k);
    float4 f0 = src[0], f1 = src[1];
    short8 s;
    s[0] = f2bf(f0.x); s[1] = f2bf(f0.y); s[2] = f2bf(f0.z); s[3] = f2bf(f0.w);
    s[4] = f2bf(f1.x); s[5] = f2bf(f1.y); s[6] = f2bf(f1.z); s[7] = f2bf(f1.w);
    *(short8*)&wfr[(long)tid * 8] = s;
}

// ---------------- kernel 1: qk GEMM + elu+1 -> q,k bf16 ; also emits xbf ----------------
// A staged once in LDS (1 barrier); B streamed coalesced from wfr; 144 MFMA/wave.
#define APAD 200
__global__ __launch_bounds__(512)
void k1_gemm(const float* __restrict__ x, const __hip_bfloat16* __restrict__ wfr,
             const float* __restrict__ qkb,
             __hip_bfloat16* __restrict__ qws, __hip_bfloat16* __restrict__ kws,
             __hip_bfloat16* __restrict__ xbf)
{
    __shared__ __align__(16) __hip_bfloat16 A_lds[128 * APAD];

    const int tid  = threadIdx.x;
    const int wid  = tid >> 6, lane = tid & 63;
    const int wm   = wid >> 1, wn = wid & 1;
    const int lrow = lane & 15;
    const int l4   = lane >> 4;
    const long rowBase = (long)blockIdx.x * 128;

    // ---- stage A (x -> bf16) for all K + emit xbf; no barriers inside ----
    {
        const int r = tid >> 2, cc = (tid & 3) * 8;
        const float* srcb = x + (rowBase + r) * CC + cc;
        __hip_bfloat16* xb = xbf + (rowBase + r) * CC + cc;
#pragma unroll
        for (int ks = 0; ks < 6; ++ks) {
            const float4* src = (const float4*)(srcb + ks * 32);
            float4 f0 = src[0], f1 = src[1];
            short8 s;
            s[0] = f2bf(f0.x); s[1] = f2bf(f0.y); s[2] = f2bf(f0.z); s[3] = f2bf(f0.w);
            s[4] = f2bf(f1.x); s[5] = f2bf(f1.y); s[6] = f2bf(f1.z); s[7] = f2bf(f1.w);
            *(short8*)&A_lds[r * APAD + ks * 32 + cc] = s;
            *(short8*)&xb[ks * 32] = s;
        }
    }
    __syncthreads();

    // ---- preload 12 A fragments ----
    short8 afr[2][6];
#pragma unroll
    for (int mi = 0; mi < 2; ++mi)
#pragma unroll
        for (int ks = 0; ks < 6; ++ks)
            afr[mi][ks] = *(const short8*)&A_lds[(wm * 32 + mi * 16 + lrow) * APAD + ks * 32 + l4 * 8];

    floatx4 acc[2][12];
#pragma unroll
    for (int i = 0; i < 2; ++i)
#pragma unroll
        for (int j = 0; j < 12; ++j) acc[i][j] = (floatx4)0.f;

    // ---- K-loop: coalesced B fragment loads + MFMA ----
    const short8* bp = (const short8*)wfr + (long)wn * 12 * 6 * 64 + lane;
#pragma unroll
    for (int ni = 0; ni < 12; ++ni) {
#pragma unroll
        for (int ks = 0; ks < 6; ++ks) {
            short8 bf = bp[(ni * 6 + ks) * 64];
            acc[0][ni] = __builtin_amdgcn_mfma_f32_16x16x32_bf16(afr[0][ks], bf, acc[0][ni], 0, 0, 0);
            acc[1][ni] = __builtin_amdgcn_mfma_f32_16x16x32_bf16(afr[1][ks], bf, acc[1][ni], 0, 0, 0);
        }
    }

    // ---- epilogue: +bias, elu+1, write bf16 (unchanged) ----
    __hip_bfloat16* dstbase = wn ? kws : qws;
#pragma unroll
    for (int ni = 0; ni < 12; ++ni) {
        int col_l = ni * 16 + lrow;
        float bias = qkb[wn * 192 + col_l];
#pragma unroll
        for (int mi = 0; mi < 2; ++mi) {
#pragma unroll
            for (int r = 0; r < 4; ++r) {
                int rowl = wm * 32 + mi * 16 + l4 * 4 + r;
                long rowg = rowBase + rowl;
                float v = acc[mi][ni][r] + bias;
                v = (v > 0.f) ? (v + 1.f) : expf(v);
                dstbase[rowg * CC + col_l] = __float2bfloat16(v);
            }
        }
    }
}

// ---------------- kernel 2: kv = (1/4096) k_rope^T v ; kmean ----------------
__global__ __launch_bounds__(256)
void k2_kv(const __hip_bfloat16* __restrict__ kws, const __hip_bfloat16* __restrict__ xbf,
           const float2* __restrict__ tab, float* __restrict__ kv, float* __restrict__ kmean)
{
    int bid = blockIdx.x;
    int chunk = bid & 7;
    int hd = (bid >> 3) % NHEAD;
    int b = bid / (8 * NHEAD);
    int tid = threadIdx.x;

    __shared__ __align__(16) float kr_s[128][36];
    __shared__ __align__(16) float v_s[128][36];
    __shared__ float km_s[32];

    if (tid < 32) km_s[tid] = 0.f;

    const int e_g = tid & 31, g = tid >> 5, d4 = g * 4;
    const int krow = tid >> 2, kq = tid & 3;   // 64 rows/pass

    float acc0 = 0.f, acc1 = 0.f, acc2 = 0.f, acc3 = 0.f;
    float msum[8];
#pragma unroll
    for (int j = 0; j < 8; ++j) msum[j] = 0.f;

    const int n0 = chunk * 512;
    const long rb = (long)b * CN;

    for (int batch = 0; batch < 4; ++batch) {
        const int nb = n0 + batch * 128;
        if (batch) __syncthreads();
        // --- load+rope k: 2 passes of 64 rows ---
#pragma unroll
        for (int p = 0; p < 2; ++p) {
            int r = p * 64 + krow;
            int n = nb + r;
            short8 kq8 = *(const short8*)&kws[(rb + n) * CC + hd * DHEAD + kq * 8];
            float kf[8];
#pragma unroll
            for (int j = 0; j < 8; ++j) { kf[j] = bf2f(kq8[j]); msum[j] += kf[j]; }
            const float4* tp = (const float4*)&tab[(long)n * 96 + hd * 16 + kq * 4];
            float4 t0 = tp[0], t1 = tp[1];
            float4 r0, r1;
            r0.x = kf[0]*t0.x - kf[1]*t0.y;  r0.y = kf[0]*t0.y + kf[1]*t0.x;
            r0.z = kf[2]*t0.z - kf[3]*t0.w;  r0.w = kf[2]*t0.w + kf[3]*t0.z;
            r1.x = kf[4]*t1.x - kf[5]*t1.y;  r1.y = kf[4]*t1.y + kf[5]*t1.x;
            r1.z = kf[6]*t1.z - kf[7]*t1.w;  r1.w = kf[6]*t1.w + kf[7]*t1.z;
            *(float4*)&kr_s[r][kq * 8]     = r0;
            *(float4*)&kr_s[r][kq * 8 + 4] = r1;
        }
        // --- load v (bf16): 2 passes of 64 rows ---
#pragma unroll
        for (int p = 0; p < 2; ++p) {
            int r = p * 64 + krow;
            short8 v8 = *(const short8*)&xbf[(rb + nb + r) * CC + hd * DHEAD + kq * 8];
            float4 va, vb;
            va.x = bf2f(v8[0]); va.y = bf2f(v8[1]); va.z = bf2f(v8[2]); va.w = bf2f(v8[3]);
            vb.x = bf2f(v8[4]); vb.y = bf2f(v8[5]); vb.z = bf2f(v8[6]); vb.w = bf2f(v8[7]);
            *(float4*)&v_s[r][kq * 8]     = va;
            *(float4*)&v_s[r][kq * 8 + 4] = vb;
        }
        __syncthreads();
#pragma unroll 8
        for (int r = 0; r < 128; ++r) {
            float4 k4 = *(const float4*)&kr_s[r][d4];
            float v1 = v_s[r][e_g];
            acc0 += k4.x * v1; acc1 += k4.y * v1; acc2 += k4.z * v1; acc3 += k4.w * v1;
        }
    }
    const float s = 1.f / 4096.f;
    float* kvb = kv + (long)(b * NHEAD + hd) * DHEAD * DHEAD;
    atomicAdd(&kvb[(d4 + 0) * DHEAD + e_g], acc0 * s);
    atomicAdd(&kvb[(d4 + 1) * DHEAD + e_g], acc1 * s);
    atomicAdd(&kvb[(d4 + 2) * DHEAD + e_g], acc2 * s);
    atomicAdd(&kvb[(d4 + 3) * DHEAD + e_g], acc3 * s);
    __syncthreads();
#pragma unroll
    for (int j = 0; j < 8; ++j) atomicAdd(&km_s[kq * 8 + j], msum[j]);
    __syncthreads();
    if (tid < 32) atomicAdd(&kmean[(b * NHEAD + hd) * DHEAD + tid], km_s[tid] * s);
}

// ---------------- kernel 3: out = (q_rope @ kv) * z + lepe ----------------
// XCD-swizzled blocks. Per half (96 ch): phase1 q load/rope/zden ->
// phase2 MFMA+z, attn bf16 into qa in place -> phase3 parallel LePE
// (coalesced short8 x-loads) + add + f32 store.
__global__ __launch_bounds__(256)
void k3_out(const __hip_bfloat16* __restrict__ qws, const __hip_bfloat16* __restrict__ xbf,
            const float2* __restrict__ tab, const float* __restrict__ kv,
            const float* __restrict__ kmean, const float* __restrict__ lw,
            const float* __restrict__ lb, float* __restrict__ out)
{
    int raw = blockIdx.x;
    int bid = (raw & 7) * 128 + (raw >> 3);   // 8 XCDs x 128 contiguous blocks
    int b = bid >> 6, h = bid & 63;
    int tid = threadIdx.x;
    int wave = tid >> 6, lane = tid & 63, lrow = lane & 15, l4 = lane >> 4;

    __shared__ __align__(16) __hip_bfloat16 qa[64][104];        // q_rope, then attn*z
    __shared__ __align__(16) __hip_bfloat16 kvt[NHEAD][32][36]; // [hd][e][d]
    __shared__ __align__(16) float lwT[9][192];                 // [tap][ch]
    __shared__ float lb_lds[CC];
    __shared__ float km_lds[CC];
    __shared__ float zden[64][8];

    const long nbase = (long)b * CN + h * 64;

    // ---- phase 0: stage kv^T (bf16), kmean, lb, transposed lw ----
    const float* kvsrc = kv + (long)b * NHEAD * DHEAD * DHEAD;
    for (int i = tid; i < NHEAD * DHEAD * DHEAD; i += 256) {
        int hd = i >> 10, d = (i >> 5) & 31, e = i & 31;
        kvt[hd][e][d] = __float2bfloat16(kvsrc[i]);
    }
    if (tid < CC) { km_lds[tid] = kmean[b * CC + tid]; lb_lds[tid] = lb[tid]; }
    for (int i = tid; i < CC * 9; i += 256) {
        int c = i / 9, tap = i - c * 9;
        lwT[tap][c] = lw[i];
    }
    __syncthreads();

#pragma unroll
    for (int half = 0; half < 2; ++half) {
        // ---- phase 1: q load (coalesced), rope, per-head z dots ----
#pragma unroll
        for (int it = 0; it < 3; ++it) {
            int slot = it * 256 + tid;          // 0..767 = w(64) x sub(12)
            int w = slot / 12;
            int sub = slot - w * 12;
            int c0 = half * 96 + sub * 8;
            short8 qv = *(const short8*)&qws[(nbase + w) * CC + c0];
            float q[8];
#pragma unroll
            for (int j = 0; j < 8; ++j) q[j] = bf2f(qv[j]);
            float p = 0.f;
#pragma unroll
            for (int j = 0; j < 8; ++j) p += q[j] * km_lds[c0 + j];
            p += __shfl_xor(p, 1);
            p += __shfl_xor(p, 2);
            if ((sub & 3) == 0) zden[w][half * 3 + (sub >> 2)] = p;
            int n = h * 64 + w;
            const float4* tp = (const float4*)&tab[(long)n * 96 + (c0 >> 1)];
            float4 t0 = tp[0], t1 = tp[1];
            short8 qr;
            qr[0] = f2bf(q[0]*t0.x - q[1]*t0.y);  qr[1] = f2bf(q[0]*t0.y + q[1]*t0.x);
            qr[2] = f2bf(q[2]*t0.z - q[3]*t0.w);  qr[3] = f2bf(q[2]*t0.w + q[3]*t0.z);
            qr[4] = f2bf(q[4]*t1.x - q[5]*t1.y);  qr[5] = f2bf(q[4]*t1.y + q[5]*t1.x);
            qr[6] = f2bf(q[6]*t1.z - q[7]*t1.w);  qr[7] = f2bf(q[6]*t1.w + q[7]*t1.z);
            *(short8*)&qa[w][sub * 8] = qr;
        }
        __syncthreads();

        // ---- phase 2: MFMA matvec, scale by z, attn bf16 in place ----
        const int rt = wave;                   // each wave owns rows [rt*16, rt*16+16)
        const int wbase = rt * 16 + l4 * 4;
#pragma unroll
        for (int hl = 0; hl < 3; ++hl) {
            int hd = half * 3 + hl;
            short8 a = *(const short8*)&qa[rt * 16 + lrow][hl * 32 + l4 * 8];
            float zv[4];
#pragma unroll
            for (int r = 0; r < 4; ++r) zv[r] = 1.f / (zden[wbase + r][hd] + 1e-6f);
#pragma unroll
            for (int nt = 0; nt < 2; ++nt) {
                short8 bfr = *(const short8*)&kvt[hd][nt * 16 + lrow][l4 * 8];
                floatx4 acc = __builtin_amdgcn_mfma_f32_16x16x32_bf16(a, bfr, (floatx4)0.f, 0, 0, 0);
                int col_l = hl * 32 + nt * 16 + lrow;   // within half
#pragma unroll
                for (int r = 0; r < 4; ++r)
                    qa[wbase + r][col_l] = __float2bfloat16(acc[r] * zv[r]);
            }
        }
        __syncthreads();

        // ---- phase 3: parallel LePE (coalesced) + add attn + store ----
#pragma unroll
        for (int it = 0; it < 3; ++it) {
            int slot = it * 256 + tid;          // 0..767 = w(64) x g(12)
            int w = slot / 12;
            int g = slot - w * 12;
            int c0g = g * 8;
            int c0 = half * 96 + c0g;
            float vals[8];
#pragma unroll
            for (int j = 0; j < 8; ++j) vals[j] = lb_lds[c0 + j];
#pragma unroll
            for (int dy = 0; dy < 3; ++dy) {
                int hy = h + dy - 1;
                if (hy < 0 || hy > 63) continue;
                const short* base = (const short*)xbf + (((long)b * 64 + hy) * 64) * CC + c0;
#pragma unroll
                for (int dx = 0; dx < 3; ++dx) {
                    int wx = w + dx - 1;
                    if (wx < 0 || wx > 63) continue;
                    short8 xv = *(const short8*)&base[(long)wx * CC];
                    const float4* wt4 = (const float4*)&lwT[dy * 3 + dx][c0];
                    float4 wa = wt4[0], wb = wt4[1];
                    vals[0] += bf2f(xv[0]) * wa.x;  vals[1] += bf2f(xv[1]) * wa.y;
                    vals[2] += bf2f(xv[2]) * wa.z;  vals[3] += bf2f(xv[3]) * wa.w;
                    vals[4] += bf2f(xv[4]) * wb.x;  vals[5] += bf2f(xv[5]) * wb.y;
                    vals[6] += bf2f(xv[6]) * wb.z;  vals[7] += bf2f(xv[7]) * wb.w;
                }
            }
            short8 at = *(const short8*)&qa[w][c0g];
#pragma unroll
            for (int j = 0; j < 8; ++j) vals[j] += bf2f(at[j]);
            float4 o0, o1;
            o0.x = vals[0]; o0.y = vals[1]; o0.z = vals[2]; o0.w = vals[3];
            o1.x = vals[4]; o1.y = vals[5]; o1.z = vals[6]; o1.w = vals[7];
            float* op = &out[(nbase + w) * CC + c0];
            *(float4*)op = o0;
            *(float4*)(op + 4) = o1;
        }
        __syncthreads();   // qa/zden reuse in next half
    }
}

extern "C" void kernel_launch(void* const* d_in, const int* in_sizes, int n_in,
                              void* d_out, int out_size, void* d_ws, size_t ws_size,
                              hipStream_t stream)
{
    const float* x   = (const float*)d_in[0];
    const float* qkw = (const float*)d_in[1];
    const float* qkb = (const float*)d_in[2];
    const float* lw  = (const float*)d_in[3];
    const float* lb  = (const float*)d_in[4];
    float* out = (float*)d_out;

    char* ws = (char*)d_ws;
    float2* tab = (float2*)ws;                 ws += (size_t)CN * 96 * sizeof(float2);
    __hip_bfloat16* qws = (__hip_bfloat16*)ws; ws += (size_t)16 * CN * CC * 2;
    __hip_bfloat16* kws = (__hip_bfloat16*)ws; ws += (size_t)16 * CN * CC * 2;
    __hip_bfloat16* xbf = (__hip_bfloat16*)ws; ws += (size_t)16 * CN * CC * 2;
    __hip_bfloat16* wfr = (__hip_bfloat16*)ws; ws += (size_t)24 * 6 * 64 * 8 * 2;
    float* kv = (float*)ws;                    ws += (size_t)16 * NHEAD * DHEAD * DHEAD * 4;
    float* km = (float*)ws;                    ws += (size_t)16 * NHEAD * DHEAD * 4;

    const int nzero = 16 * NHEAD * DHEAD * DHEAD + 16 * NHEAD * DHEAD;
    k_zero<<<(nzero + 255) / 256, 256, 0, stream>>>(kv, nzero);
    k0_table<<<(CN * 96 + 255) / 256, 256, 0, stream>>>(tab);
    k0_wfrag<<<36, 256, 0, stream>>>(qkw, wfr);
    k1_gemm<<<512, 512, 0, stream>>>(x, wfr, qkb, qws, kws, xbf);
    k2_kv<<<16 * NHEAD * 8, 256, 0, stream>>>(kws, xbf, tab, kv, km);
    k3_out<<<16 * 64, 256, 0, stream>>>(qws, xbf, tab, kv, km, lw, lb, out);
}

// Round 7
// 115.243 us; speedup vs baseline: 1.2106x; 1.2106x over previous
//
#include <hip/hip_runtime.h>
#include <hip/hip_bf16.h>

using short8  = __attribute__((ext_vector_type(8))) short;
using floatx4 = __attribute__((ext_vector_type(4))) float;

#define CC 192
#define CN 4096
#define NHEAD 6
#define DHEAD 32

__device__ __forceinline__ float bf2f(short s) {
    return __uint_as_float(((unsigned)(unsigned short)s) << 16);
}
__device__ __forceinline__ short f2bf(float f) {
    __hip_bfloat16 h = __float2bfloat16(f);
    return *(short*)&h;
}

// ---------------- kernel 0: rope cos/sin table ----------------
__global__ void k0_table(float2* __restrict__ tab) {
    int idx = blockIdx.x * 256 + threadIdx.x;
    if (idx >= CN * 96) return;
    int n = idx / 96, c2 = idx - n * 96;
    int h = n >> 6, w = n & 63;
    int i = (c2 < 48) ? c2 : c2 - 48;
    float pos = (float)((c2 < 48) ? h : w);
    float theta = expf(-(float)i * (9.210340371976184f / 48.0f)); // ln(10000)/48
    float ang = pos * theta;
    tab[idx] = make_float2(cosf(ang), sinf(ang));
}

__global__ void k_zero(float* __restrict__ p, int n) {
    int i = blockIdx.x * 256 + threadIdx.x;
    if (i < n) p[i] = 0.f;
}

// ---------------- kernel 0w: pre-fragment qk_w into bf16 MFMA-B layout ----------------
// wfr[((nig*6+ks)*64 + lane) * 8 + j] = bf16(qkw[col][k]),
// col = nig*16 + (lane&15), k = ks*32 + (lane>>4)*8 + j
__global__ void k0_wfrag(const float* __restrict__ qkw, __hip_bfloat16* __restrict__ wfr) {
    int tid = blockIdx.x * 256 + threadIdx.x;     // 0..9215
    if (tid >= 24 * 6 * 64) return;
    int lane = tid & 63;
    int ks = (tid >> 6) % 6;
    int nig = tid / (6 * 64);
    int col = nig * 16 + (lane & 15);
    int k = ks * 32 + (lane >> 4) * 8;
    const float4* src = (const float4*)(qkw + (long)col * CC + k);
    float4 f0 = src[0], f1 = src[1];
    short8 s;
    s[0] = f2bf(f0.x); s[1] = f2bf(f0.y); s[2] = f2bf(f0.z); s[3] = f2bf(f0.w);
    s[4] = f2bf(f1.x); s[5] = f2bf(f1.y); s[6] = f2bf(f1.z); s[7] = f2bf(f1.w);
    *(short8*)&wfr[(long)tid * 8] = s;
}

// ---------------- kernel 1: qk GEMM + elu+1 -> q,k bf16 ; also emits xbf ----------------
// Round-5 structure (per-step LDS staging), but B staged as a pure bf16 copy
// from wfr in fragment order: zero B conversions, conflict-free LDS access.
#define LDSP 40
__global__ __launch_bounds__(512)
void k1_gemm(const float* __restrict__ x, const __hip_bfloat16* __restrict__ wfr,
             const float* __restrict__ qkb,
             __hip_bfloat16* __restrict__ qws, __hip_bfloat16* __restrict__ kws,
             __hip_bfloat16* __restrict__ xbf)
{
    __shared__ __align__(16) __hip_bfloat16 A_lds[128 * LDSP];
    __shared__ __align__(16) __hip_bfloat16 B_lds[24 * 512];   // [nig][lane*8], one K-step

    const int tid  = threadIdx.x;
    const int wid  = tid >> 6, lane = tid & 63;
    const int wm   = wid >> 1, wn = wid & 1;
    const int lrow = lane & 15;
    const int l4   = lane >> 4;
    const int lk   = l4 * 8;
    const long rowBase = (long)blockIdx.x * 128;

    const int ar = tid >> 2, acc_c = (tid & 3) * 8;   // A-stage coords

    floatx4 acc[2][12];
#pragma unroll
    for (int i = 0; i < 2; ++i)
#pragma unroll
        for (int j = 0; j < 12; ++j) acc[i][j] = (floatx4)0.f;

    for (int ks = 0; ks < 6; ++ks) {
        const int k0 = ks * 32;

        // ---- issue global loads for this step's staging (before barrier:
        //      overlaps previous step's compute) ----
        short8 bstage[3];
#pragma unroll
        for (int j = 0; j < 3; ++j) {
            int s = j * 512 + tid;            // 0..1535 = nig(24) x lane(64)
            int nig = s >> 6, ln = s & 63;
            bstage[j] = *(const short8*)&wfr[((long)(nig * 6 + ks) * 64 + ln) * 8];
        }
        const float4* asrc = (const float4*)(x + (rowBase + ar) * CC + k0 + acc_c);
        float4 f0 = asrc[0], f1 = asrc[1];
        short8 as;
        as[0] = f2bf(f0.x); as[1] = f2bf(f0.y); as[2] = f2bf(f0.z); as[3] = f2bf(f0.w);
        as[4] = f2bf(f1.x); as[5] = f2bf(f1.y); as[6] = f2bf(f1.z); as[7] = f2bf(f1.w);

        if (ks) __syncthreads();              // prev-step LDS reads done

        *(short8*)&A_lds[ar * LDSP + acc_c] = as;
        *(short8*)&xbf[(rowBase + ar) * CC + k0 + acc_c] = as;
#pragma unroll
        for (int j = 0; j < 3; ++j) {
            int s = j * 512 + tid;
            *(short8*)&B_lds[s * 8] = bstage[j];
        }
        __syncthreads();

        // ---- compute: 24 MFMA per wave ----
        short8 a0 = *(const short8*)&A_lds[(wm * 32 + lrow) * LDSP + lk];
        short8 a1 = *(const short8*)&A_lds[(wm * 32 + 16 + lrow) * LDSP + lk];
#pragma unroll
        for (int ni = 0; ni < 12; ++ni) {
            short8 bf = *(const short8*)&B_lds[(wn * 12 + ni) * 512 + lane * 8];
            acc[0][ni] = __builtin_amdgcn_mfma_f32_16x16x32_bf16(a0, bf, acc[0][ni], 0, 0, 0);
            acc[1][ni] = __builtin_amdgcn_mfma_f32_16x16x32_bf16(a1, bf, acc[1][ni], 0, 0, 0);
        }
    }

    // ---- epilogue: +bias, elu+1, write bf16 ----
    __hip_bfloat16* dstbase = wn ? kws : qws;
#pragma unroll
    for (int ni = 0; ni < 12; ++ni) {
        int col_l = ni * 16 + lrow;
        float bias = qkb[wn * 192 + col_l];
#pragma unroll
        for (int mi = 0; mi < 2; ++mi) {
#pragma unroll
            for (int r = 0; r < 4; ++r) {
                int rowl = wm * 32 + mi * 16 + l4 * 4 + r;
                long rowg = rowBase + rowl;
                float v = acc[mi][ni][r] + bias;
                v = (v > 0.f) ? (v + 1.f) : expf(v);
                dstbase[rowg * CC + col_l] = __float2bfloat16(v);
            }
        }
    }
}

// ---------------- kernel 2: kv = (1/4096) k_rope^T v ; kmean ----------------
__global__ __launch_bounds__(256)
void k2_kv(const __hip_bfloat16* __restrict__ kws, const __hip_bfloat16* __restrict__ xbf,
           const float2* __restrict__ tab, float* __restrict__ kv, float* __restrict__ kmean)
{
    int bid = blockIdx.x;
    int chunk = bid & 7;
    int hd = (bid >> 3) % NHEAD;
    int b = bid / (8 * NHEAD);
    int tid = threadIdx.x;

    __shared__ __align__(16) float kr_s[128][36];
    __shared__ __align__(16) float v_s[128][36];
    __shared__ float km_s[32];

    if (tid < 32) km_s[tid] = 0.f;

    const int e_g = tid & 31, g = tid >> 5, d4 = g * 4;
    const int krow = tid >> 2, kq = tid & 3;   // 64 rows/pass

    float acc0 = 0.f, acc1 = 0.f, acc2 = 0.f, acc3 = 0.f;
    float msum[8];
#pragma unroll
    for (int j = 0; j < 8; ++j) msum[j] = 0.f;

    const int n0 = chunk * 512;
    const long rb = (long)b * CN;

    for (int batch = 0; batch < 4; ++batch) {
        const int nb = n0 + batch * 128;
        if (batch) __syncthreads();
        // --- load+rope k: 2 passes of 64 rows ---
#pragma unroll
        for (int p = 0; p < 2; ++p) {
            int r = p * 64 + krow;
            int n = nb + r;
            short8 kq8 = *(const short8*)&kws[(rb + n) * CC + hd * DHEAD + kq * 8];
            float kf[8];
#pragma unroll
            for (int j = 0; j < 8; ++j) { kf[j] = bf2f(kq8[j]); msum[j] += kf[j]; }
            const float4* tp = (const float4*)&tab[(long)n * 96 + hd * 16 + kq * 4];
            float4 t0 = tp[0], t1 = tp[1];
            float4 r0, r1;
            r0.x = kf[0]*t0.x - kf[1]*t0.y;  r0.y = kf[0]*t0.y + kf[1]*t0.x;
            r0.z = kf[2]*t0.z - kf[3]*t0.w;  r0.w = kf[2]*t0.w + kf[3]*t0.z;
            r1.x = kf[4]*t1.x - kf[5]*t1.y;  r1.y = kf[4]*t1.y + kf[5]*t1.x;
            r1.z = kf[6]*t1.z - kf[7]*t1.w;  r1.w = kf[6]*t1.w + kf[7]*t1.z;
            *(float4*)&kr_s[r][kq * 8]     = r0;
            *(float4*)&kr_s[r][kq * 8 + 4] = r1;
        }
        // --- load v (bf16): 2 passes of 64 rows ---
#pragma unroll
        for (int p = 0; p < 2; ++p) {
            int r = p * 64 + krow;
            short8 v8 = *(const short8*)&xbf[(rb + nb + r) * CC + hd * DHEAD + kq * 8];
            float4 va, vb;
            va.x = bf2f(v8[0]); va.y = bf2f(v8[1]); va.z = bf2f(v8[2]); va.w = bf2f(v8[3]);
            vb.x = bf2f(v8[4]); vb.y = bf2f(v8[5]); vb.z = bf2f(v8[6]); vb.w = bf2f(v8[7]);
            *(float4*)&v_s[r][kq * 8]     = va;
            *(float4*)&v_s[r][kq * 8 + 4] = vb;
        }
        __syncthreads();
#pragma unroll 8
        for (int r = 0; r < 128; ++r) {
            float4 k4 = *(const float4*)&kr_s[r][d4];
            float v1 = v_s[r][e_g];
            acc0 += k4.x * v1; acc1 += k4.y * v1; acc2 += k4.z * v1; acc3 += k4.w * v1;
        }
    }
    const float s = 1.f / 4096.f;
    float* kvb = kv + (long)(b * NHEAD + hd) * DHEAD * DHEAD;
    atomicAdd(&kvb[(d4 + 0) * DHEAD + e_g], acc0 * s);
    atomicAdd(&kvb[(d4 + 1) * DHEAD + e_g], acc1 * s);
    atomicAdd(&kvb[(d4 + 2) * DHEAD + e_g], acc2 * s);
    atomicAdd(&kvb[(d4 + 3) * DHEAD + e_g], acc3 * s);
    __syncthreads();
#pragma unroll
    for (int j = 0; j < 8; ++j) atomicAdd(&km_s[kq * 8 + j], msum[j]);
    __syncthreads();
    if (tid < 32) atomicAdd(&kmean[(b * NHEAD + hd) * DHEAD + tid], km_s[tid] * s);
}

// ---------------- kernel 3: out = (q_rope @ kv) * z + lepe ----------------
// XCD-swizzled blocks. Per half (96 ch): phase1 q load/rope/zden ->
// phase2 MFMA+z, attn bf16 into qa in place -> phase3 parallel LePE
// (coalesced short8 x-loads) + add + f32 store.
__global__ __launch_bounds__(256)
void k3_out(const __hip_bfloat16* __restrict__ qws, const __hip_bfloat16* __restrict__ xbf,
            const float2* __restrict__ tab, const float* __restrict__ kv,
            const float* __restrict__ kmean, const float* __restrict__ lw,
            const float* __restrict__ lb, float* __restrict__ out)
{
    int raw = blockIdx.x;
    int bid = (raw & 7) * 128 + (raw >> 3);   // 8 XCDs x 128 contiguous blocks
    int b = bid >> 6, h = bid & 63;
    int tid = threadIdx.x;
    int wave = tid >> 6, lane = tid & 63, lrow = lane & 15, l4 = lane >> 4;

    __shared__ __align__(16) __hip_bfloat16 qa[64][104];        // q_rope, then attn*z
    __shared__ __align__(16) __hip_bfloat16 kvt[NHEAD][32][36]; // [hd][e][d]
    __shared__ __align__(16) float lwT[9][192];                 // [tap][ch]
    __shared__ float lb_lds[CC];
    __shared__ float km_lds[CC];
    __shared__ float zden[64][8];

    const long nbase = (long)b * CN + h * 64;

    // ---- phase 0: stage kv^T (bf16), kmean, lb, transposed lw ----
    const float* kvsrc = kv + (long)b * NHEAD * DHEAD * DHEAD;
    for (int i = tid; i < NHEAD * DHEAD * DHEAD; i += 256) {
        int hd = i >> 10, d = (i >> 5) & 31, e = i & 31;
        kvt[hd][e][d] = __float2bfloat16(kvsrc[i]);
    }
    if (tid < CC) { km_lds[tid] = kmean[b * CC + tid]; lb_lds[tid] = lb[tid]; }
    for (int i = tid; i < CC * 9; i += 256) {
        int c = i / 9, tap = i - c * 9;
        lwT[tap][c] = lw[i];
    }
    __syncthreads();

#pragma unroll
    for (int half = 0; half < 2; ++half) {
        // ---- phase 1: q load (coalesced), rope, per-head z dots ----
#pragma unroll
        for (int it = 0; it < 3; ++it) {
            int slot = it * 256 + tid;          // 0..767 = w(64) x sub(12)
            int w = slot / 12;
            int sub = slot - w * 12;
            int c0 = half * 96 + sub * 8;
            short8 qv = *(const short8*)&qws[(nbase + w) * CC + c0];
            float q[8];
#pragma unroll
            for (int j = 0; j < 8; ++j) q[j] = bf2f(qv[j]);
            float p = 0.f;
#pragma unroll
            for (int j = 0; j < 8; ++j) p += q[j] * km_lds[c0 + j];
            p += __shfl_xor(p, 1);
            p += __shfl_xor(p, 2);
            if ((sub & 3) == 0) zden[w][half * 3 + (sub >> 2)] = p;
            int n = h * 64 + w;
            const float4* tp = (const float4*)&tab[(long)n * 96 + (c0 >> 1)];
            float4 t0 = tp[0], t1 = tp[1];
            short8 qr;
            qr[0] = f2bf(q[0]*t0.x - q[1]*t0.y);  qr[1] = f2bf(q[0]*t0.y + q[1]*t0.x);
            qr[2] = f2bf(q[2]*t0.z - q[3]*t0.w);  qr[3] = f2bf(q[2]*t0.w + q[3]*t0.z);
            qr[4] = f2bf(q[4]*t1.x - q[5]*t1.y);  qr[5] = f2bf(q[4]*t1.y + q[5]*t1.x);
            qr[6] = f2bf(q[6]*t1.z - q[7]*t1.w);  qr[7] = f2bf(q[6]*t1.w + q[7]*t1.z);
            *(short8*)&qa[w][sub * 8] = qr;
        }
        __syncthreads();

        // ---- phase 2: MFMA matvec, scale by z, attn bf16 in place ----
        const int rt = wave;                   // each wave owns rows [rt*16, rt*16+16)
        const int wbase = rt * 16 + l4 * 4;
#pragma unroll
        for (int hl = 0; hl < 3; ++hl) {
            int hd = half * 3 + hl;
            short8 a = *(const short8*)&qa[rt * 16 + lrow][hl * 32 + l4 * 8];
            float zv[4];
#pragma unroll
            for (int r = 0; r < 4; ++r) zv[r] = 1.f / (zden[wbase + r][hd] + 1e-6f);
#pragma unroll
            for (int nt = 0; nt < 2; ++nt) {
                short8 bfr = *(const short8*)&kvt[hd][nt * 16 + lrow][l4 * 8];
                floatx4 acc = __builtin_amdgcn_mfma_f32_16x16x32_bf16(a, bfr, (floatx4)0.f, 0, 0, 0);
                int col_l = hl * 32 + nt * 16 + lrow;   // within half
#pragma unroll
                for (int r = 0; r < 4; ++r)
                    qa[wbase + r][col_l] = __float2bfloat16(acc[r] * zv[r]);
            }
        }
        __syncthreads();

        // ---- phase 3: parallel LePE (coalesced) + add attn + store ----
#pragma unroll
        for (int it = 0; it < 3; ++it) {
            int slot = it * 256 + tid;          // 0..767 = w(64) x g(12)
            int w = slot / 12;
            int g = slot - w * 12;
            int c0g = g * 8;
            int c0 = half * 96 + c0g;
            float vals[8];
#pragma unroll
            for (int j = 0; j < 8; ++j) vals[j] = lb_lds[c0 + j];
#pragma unroll
            for (int dy = 0; dy < 3; ++dy) {
                int hy = h + dy - 1;
                if (hy < 0 || hy > 63) continue;
                const short* base = (const short*)xbf + (((long)b * 64 + hy) * 64) * CC + c0;
#pragma unroll
                for (int dx = 0; dx < 3; ++dx) {
                    int wx = w + dx - 1;
                    if (wx < 0 || wx > 63) continue;
                    short8 xv = *(const short8*)&base[(long)wx * CC];
                    const float4* wt4 = (const float4*)&lwT[dy * 3 + dx][c0];
                    float4 wa = wt4[0], wb = wt4[1];
                    vals[0] += bf2f(xv[0]) * wa.x;  vals[1] += bf2f(xv[1]) * wa.y;
                    vals[2] += bf2f(xv[2]) * wa.z;  vals[3] += bf2f(xv[3]) * wa.w;
                    vals[4] += bf2f(xv[4]) * wb.x;  vals[5] += bf2f(xv[5]) * wb.y;
                    vals[6] += bf2f(xv[6]) * wb.z;  vals[7] += bf2f(xv[7]) * wb.w;
                }
            }
            short8 at = *(const short8*)&qa[w][c0g];
#pragma unroll
            for (int j = 0; j < 8; ++j) vals[j] += bf2f(at[j]);
            float4 o0, o1;
            o0.x = vals[0]; o0.y = vals[1]; o0.z = vals[2]; o0.w = vals[3];
            o1.x = vals[4]; o1.y = vals[5]; o1.z = vals[6]; o1.w = vals[7];
            float* op = &out[(nbase + w) * CC + c0];
            *(float4*)op = o0;
            *(float4*)(op + 4) = o1;
        }
        __syncthreads();   // qa/zden reuse in next half
    }
}

extern "C" void kernel_launch(void* const* d_in, const int* in_sizes, int n_in,
                              void* d_out, int out_size, void* d_ws, size_t ws_size,
                              hipStream_t stream)
{
    const float* x   = (const float*)d_in[0];
    const float* qkw = (const float*)d_in[1];
    const float* qkb = (const float*)d_in[2];
    const float* lw  = (const float*)d_in[3];
    const float* lb  = (const float*)d_in[4];
    float* out = (float*)d_out;

    char* ws = (char*)d_ws;
    float2* tab = (float2*)ws;                 ws += (size_t)CN * 96 * sizeof(float2);
    __hip_bfloat16* qws = (__hip_bfloat16*)ws; ws += (size_t)16 * CN * CC * 2;
    __hip_bfloat16* kws = (__hip_bfloat16*)ws; ws += (size_t)16 * CN * CC * 2;
    __hip_bfloat16* xbf = (__hip_bfloat16*)ws; ws += (size_t)16 * CN * CC * 2;
    __hip_bfloat16* wfr = (__hip_bfloat16*)ws; ws += (size_t)24 * 6 * 64 * 8 * 2;
    float* kv = (float*)ws;                    ws += (size_t)16 * NHEAD * DHEAD * DHEAD * 4;
    float* km = (float*)ws;                    ws += (size_t)16 * NHEAD * DHEAD * 4;

    const int nzero = 16 * NHEAD * DHEAD * DHEAD + 16 * NHEAD * DHEAD;
    k_zero<<<(nzero + 255) / 256, 256, 0, stream>>>(kv, nzero);
    k0_table<<<(CN * 96 + 255) / 256, 256, 0, stream>>>(tab);
    k0_wfrag<<<36, 256, 0, stream>>>(qkw, wfr);
    k1_gemm<<<512, 512, 0, stream>>>(x, wfr, qkb, qws, kws, xbf);
    k2_kv<<<16 * NHEAD * 8, 256, 0, stream>>>(kws, xbf, tab, kv, km);
    k3_out<<<16 * 64, 256, 0, stream>>>(qws, xbf, tab, kv, km, lw, lb, out);
}